// Round 8
// baseline (2383.078 us; speedup 1.0000x reference)
//
#include <hip/hip_runtime.h>
#include <hip/hip_bf16.h>
#include <stdint.h>

#define BB 4
#define TT 64
#define NN 4096
#define HH 128
#define EE 65536
#define BN (BB*NN)   // 16384

typedef __attribute__((ext_vector_type(8))) short short8;
typedef __attribute__((ext_vector_type(4))) float f32x4;

__device__ __forceinline__ unsigned short bf16r(float f) {
    unsigned u = __float_as_uint(f);
    u += 0x7fffu + ((u >> 16) & 1u);
    return (unsigned short)(u >> 16);
}
__device__ __forceinline__ float bf2f(unsigned bits16) {
    return __uint_as_float(bits16 << 16);
}
__device__ __forceinline__ float sigm(float x) { return 1.f / (1.f + __expf(-x)); }
__device__ __forceinline__ float tanhfast(float x) {
    return 1.f - 2.f / (__expf(2.f * x) + 1.f);
}
// byte address within a [64][128]-bf16 LDS tile, XOR-swizzled
__device__ __forceinline__ unsigned swz(int row, int colbyte) {
    return (unsigned)(row * 256 + (colbyte ^ ((row & 7) << 4)));
}

// ================= packs =================
// WcbP: [half][nt(8)][ks(4)][lane(64)][8].  half0: Wc = W_msg@W_mix[0:128]; half1: W_mix[128:256]
__global__ void pack_wcb_kernel(const float* __restrict__ W_msg, const float* __restrict__ W_mix,
                                short* __restrict__ out)
{
    int idx = blockIdx.x * 256 + threadIdx.x;   // 4096
    if (idx >= 4096) return;
    int l = idx & 63, ks = (idx >> 6) & 3, nt = (idx >> 8) & 7, half = idx >> 11;
    int lo = l & 15, hi = l >> 4;
    int col = nt * 16 + lo;
    short8 v;
    #pragma unroll
    for (int i = 0; i < 8; ++i) {
        int k = ks * 32 + hi * 8 + i;
        float s;
        if (half == 0) {
            s = 0.f;
            for (int j = 0; j < 128; ++j) s += W_msg[k * 128 + j] * W_mix[j * 128 + col];
        } else {
            s = W_mix[(128 + k) * 128 + col];
        }
        v[i] = (short)bf16r(s);
    }
    *(short8*)(out + (size_t)idx * 8) = v;
}

// Wp4: 32 tiles x 8 ks. nt 0-7=r, 8-15=z (ks<4 Wih / ks>=4 Whh), 16-23=i_n (Wih,ks<4), 24-31=h_n (Whh,ks>=4)
__global__ void pack_ihh_kernel(const float* __restrict__ Wih, const float* __restrict__ Whh,
                                short* __restrict__ out)
{
    int idx = blockIdx.x * 256 + threadIdx.x;   // 16384
    if (idx >= 32 * 8 * 64) return;
    int l = idx & 63, ks = (idx >> 6) & 7, nt = idx >> 9;
    int lo = l & 15, hi = l >> 4;
    short8 v;
    #pragma unroll
    for (int i = 0; i < 8; ++i) {
        int k = ks * 32 + hi * 8 + i;
        float s = 0.f;
        if (nt < 16) {
            int col = nt * 16 + lo;
            s = (ks < 4) ? Wih[k * 384 + col] : Whh[(k - 128) * 384 + col];
        } else if (nt < 24) {
            int col = 256 + (nt - 16) * 16 + lo;
            s = (ks < 4) ? Wih[k * 384 + col] : 0.f;
        } else {
            int col = 256 + (nt - 24) * 16 + lo;
            s = (ks >= 4) ? Whh[(k - 128) * 384 + col] : 0.f;
        }
        v[i] = (short)bf16r(s);
    }
    *(short8*)(out + (size_t)idx * 8) = v;
}

__global__ void pack_bias_kernel(const float* __restrict__ b_ih, const float* __restrict__ b_hh,
                                 const float* __restrict__ b_msg, const float* __restrict__ W_mix,
                                 float* __restrict__ biasRZ, float* __restrict__ bvec)
{
    int j = threadIdx.x;
    biasRZ[j]       = b_ih[j]       + b_hh[j];
    biasRZ[128 + j] = b_ih[128 + j] + b_hh[128 + j];
    float s = 0.f;
    for (int jj = 0; jj < 128; ++jj) s += b_msg[jj] * W_mix[jj * 128 + j];
    bvec[j] = s;
}

// ================= gather from f32 x: agg[bt,dst,:] = sum_src x[bt,src,:] (bf16 out) =================
__global__ __launch_bounds__(256)
void gather_all_kernel(const float* __restrict__ x,
                       const int* __restrict__ off, const int* __restrict__ srcs,
                       unsigned short* __restrict__ agg)
{
    int rb = blockIdx.x * 4 + (threadIdx.x >> 6);   // 0 .. B*T*N-1
    int l = threadIdx.x & 63;
    int dst = rb & 4095;
    int bt  = rb >> 12;
    const float* __restrict__ xr = x + (size_t)bt * NN * HH;
    int s = off[dst], e = off[dst + 1];
    float a0 = 0.f, a1 = 0.f, b0 = 0.f, b1 = 0.f;
    float c0 = 0.f, c1 = 0.f, d0 = 0.f, d1 = 0.f;
    int i = s;
    for (; i + 3 < e; i += 4) {
        int s0 = srcs[i], s1 = srcs[i + 1], s2 = srcs[i + 2], s3 = srcs[i + 3];
        float2 v0 = *(const float2*)(xr + (size_t)s0 * HH + l * 2);
        float2 v1 = *(const float2*)(xr + (size_t)s1 * HH + l * 2);
        float2 v2 = *(const float2*)(xr + (size_t)s2 * HH + l * 2);
        float2 v3 = *(const float2*)(xr + (size_t)s3 * HH + l * 2);
        a0 += v0.x; a1 += v0.y;
        b0 += v1.x; b1 += v1.y;
        c0 += v2.x; c1 += v2.y;
        d0 += v3.x; d1 += v3.y;
    }
    for (; i < e; ++i) {
        float2 v0 = *(const float2*)(xr + (size_t)srcs[i] * HH + l * 2);
        a0 += v0.x; a1 += v0.y;
    }
    a0 += b0 + c0 + d0; a1 += b1 + c1 + d1;
    *(unsigned*)(agg + (size_t)rb * HH + l * 2) = (unsigned)bf16r(a0) | ((unsigned)bf16r(a1) << 16);
}

// ================= persistent T-loop kernel: weights in regs, async staging, 2 barriers/step =====
__global__ __launch_bounds__(512, 2)
void mega4_kernel(const float* __restrict__ x,
                  const unsigned short* __restrict__ agg,
                  const short* __restrict__ WcbP, const short* __restrict__ Wp4,
                  const float* __restrict__ degf,
                  const float* __restrict__ bvec, const float* __restrict__ b_mix,
                  const float* __restrict__ biasRZ,
                  const float* __restrict__ b_ih, const float* __restrict__ b_hh,
                  const float* __restrict__ W_ro, const float* __restrict__ b_ro,
                  const float* __restrict__ targets, const void* __restrict__ maskp,
                  const int* __restrict__ flag,
                  float* __restrict__ lossBlock)
{
    __shared__ unsigned short sAgg[64 * 128];
    __shared__ unsigned short sX0[64 * 128];
    __shared__ unsigned short sX1[64 * 128];
    __shared__ unsigned short sMi[64 * 128];
    __shared__ unsigned short sSt[64 * 128];
    __shared__ float pP[8][64];
    __shared__ float sdeg[64];

    const int tid = threadIdx.x;
    const int w = tid >> 6, l = tid & 63, lo = l & 15, hi = l >> 4;
    const int nt = w;
    const int phys = blockIdx.x;
    const int b = phys >> 6;
    const int n0 = (phys & 63) * 64;

    // ---- all B-fragments in registers, loaded once ----
    short8 wB[8], wR[8], wZ[8], wN[4], wH[4];
    #pragma unroll
    for (int ks = 0; ks < 8; ++ks) {
        wB[ks] = *(const short8*)(WcbP + (size_t)((((ks >> 2) * 8 + nt) * 4 + (ks & 3)) * 64 + l) * 8);
        wR[ks] = *(const short8*)(Wp4 + (size_t)((nt * 8 + ks) * 64 + l) * 8);
        wZ[ks] = *(const short8*)(Wp4 + (size_t)(((8 + nt) * 8 + ks) * 64 + l) * 8);
    }
    #pragma unroll
    for (int ks = 0; ks < 4; ++ks) {
        wN[ks] = *(const short8*)(Wp4 + (size_t)(((16 + nt) * 8 + ks) * 64 + l) * 8);
        wH[ks] = *(const short8*)(Wp4 + (size_t)(((24 + nt) * 8 + (ks + 4)) * 64 + l) * 8);
    }

    const int jcol = nt * 16 + lo;
    const float br = biasRZ[jcol], bz = biasRZ[128 + jcol];
    const float bi = b_ih[256 + jcol], bh = b_hh[256 + jcol];
    const float wro = W_ro[jcol];
    const float bv = bvec[jcol], bm = b_mix[jcol];
    const float bro = b_ro[0];
    const int fl = *flag;

    // staging decomposition: thread -> (row, seg): 64 B of f32 x, 32 B of bf16 agg
    const int srow = tid >> 3, sseg = tid & 7;
    const size_t rowbase = ((size_t)(b * TT) * NN + n0 + srow) * HH;

    // ---- prologue: stage t=0, zero state, first targets prefetch ----
    {
        const float* xp = x + rowbase + sseg * 16;
        float4 v0 = *(const float4*)xp, v1 = *(const float4*)(xp + 4);
        float4 v2 = *(const float4*)(xp + 8), v3 = *(const float4*)(xp + 12);
        short8 p0, p1;
        p0[0]=(short)bf16r(v0.x); p0[1]=(short)bf16r(v0.y); p0[2]=(short)bf16r(v0.z); p0[3]=(short)bf16r(v0.w);
        p0[4]=(short)bf16r(v1.x); p0[5]=(short)bf16r(v1.y); p0[6]=(short)bf16r(v1.z); p0[7]=(short)bf16r(v1.w);
        p1[0]=(short)bf16r(v2.x); p1[1]=(short)bf16r(v2.y); p1[2]=(short)bf16r(v2.z); p1[3]=(short)bf16r(v2.w);
        p1[4]=(short)bf16r(v3.x); p1[5]=(short)bf16r(v3.y); p1[6]=(short)bf16r(v3.z); p1[7]=(short)bf16r(v3.w);
        *(short8*)((char*)sX0 + swz(srow, sseg * 32)) = p0;
        *(short8*)((char*)sX0 + swz(srow, sseg * 32 + 16)) = p1;
        const unsigned short* ap = agg + rowbase + sseg * 16;
        *(short8*)((char*)sAgg + swz(srow, sseg * 32)) = *(const short8*)ap;
        *(short8*)((char*)sAgg + swz(srow, sseg * 32 + 16)) = *(const short8*)(ap + 8);
    }
    #pragma unroll
    for (int it = 0; it < 8; ++it) ((unsigned*)sSt)[tid + it * 512] = 0u;
    if (tid < 64) sdeg[tid] = degf[n0 + tid];

    float tgtReg = 0.f, mvReg = 0.f, lossAcc = 0.f;
    if (tid < 64) {
        size_t ti = (size_t)(b * TT) * NN + n0 + tid;
        tgtReg = targets[ti];
        mvReg = fl ? (((const unsigned char*)maskp)[ti] ? 1.f : 0.f)
                   : (((const int*)maskp)[ti] ? 1.f : 0.f);
    }
    __syncthreads();

    unsigned short* sXc = sX0;
    unsigned short* sXn = sX1;

    for (int t = 0; t < TT; ++t) {
        // ---- loss consume for t-1 (pP ordered by previous bar1) ----
        float tgtNew = tgtReg, mvNew = mvReg;
        if (tid < 64) {
            if (t > 0) {
                float out = bro;
                #pragma unroll
                for (int ww = 0; ww < 8; ++ww) out += pP[ww][tid];
                float d = out - tgtReg;
                lossAcc += 0.5f * d * d * mvReg;
            }
            // prefetch targets/mask for t (consumed at top of t+1)
            size_t ti = (size_t)(b * TT + t) * NN + n0 + tid;
            tgtNew = targets[ti];
            mvNew = fl ? (((const unsigned char*)maskp)[ti] ? 1.f : 0.f)
                       : (((const int*)maskp)[ti] ? 1.f : 0.f);
        }
        tgtReg = tgtNew; mvReg = mvNew;

        // ---- prefetch next step's x/agg into registers ----
        float4 rx0, rx1, rx2, rx3; short8 ra0, ra1;
        const bool havenext = (t < TT - 1);
        if (havenext) {
            const size_t nb = rowbase + (size_t)(t + 1) * NN * HH;
            const float* xp = x + nb + sseg * 16;
            rx0 = *(const float4*)xp;       rx1 = *(const float4*)(xp + 4);
            rx2 = *(const float4*)(xp + 8); rx3 = *(const float4*)(xp + 12);
            const unsigned short* ap = agg + nb + sseg * 16;
            ra0 = *(const short8*)ap; ra1 = *(const short8*)(ap + 8);
        }

        // ---- B: mi = agg@Wc + state@Wb + deg*bvec + b_mix ----
        f32x4 mAcc[4] = {};
        #pragma unroll
        for (int ks = 0; ks < 8; ++ks) {
            #pragma unroll
            for (int s4 = 0; s4 < 4; ++s4) {
                short8 af = (ks < 4)
                    ? *(const short8*)((const char*)sAgg + swz(s4 * 16 + lo, ks * 64 + hi * 16))
                    : *(const short8*)((const char*)sSt + swz(s4 * 16 + lo, (ks - 4) * 64 + hi * 16));
                mAcc[s4] = __builtin_amdgcn_mfma_f32_16x16x32_bf16(af, wB[ks], mAcc[s4], 0, 0, 0);
            }
        }
        #pragma unroll
        for (int s4 = 0; s4 < 4; ++s4)
            #pragma unroll
            for (int q = 0; q < 4; ++q) {
                int row = s4 * 16 + hi * 4 + q;
                float v = mAcc[s4][q] + sdeg[row] * bv + bm;
                unsigned bits = bf16r(v);
                unsigned other = (unsigned)__shfl_xor((int)bits, 1);
                if (!(lo & 1))
                    *(unsigned*)((char*)sMi + swz(row, jcol * 2)) = bits | (other << 16);
            }
        __syncthreads();   // bar2: sMi ready; sAgg/sSt consumers done

        // ---- stage-write t+1 (sAgg free now; sXn is the spare buffer) ----
        if (havenext) {
            short8 p0, p1;
            p0[0]=(short)bf16r(rx0.x); p0[1]=(short)bf16r(rx0.y); p0[2]=(short)bf16r(rx0.z); p0[3]=(short)bf16r(rx0.w);
            p0[4]=(short)bf16r(rx1.x); p0[5]=(short)bf16r(rx1.y); p0[6]=(short)bf16r(rx1.z); p0[7]=(short)bf16r(rx1.w);
            p1[0]=(short)bf16r(rx2.x); p1[1]=(short)bf16r(rx2.y); p1[2]=(short)bf16r(rx2.z); p1[3]=(short)bf16r(rx2.w);
            p1[4]=(short)bf16r(rx3.x); p1[5]=(short)bf16r(rx3.y); p1[6]=(short)bf16r(rx3.z); p1[7]=(short)bf16r(rx3.w);
            *(short8*)((char*)sXn + swz(srow, sseg * 32)) = p0;
            *(short8*)((char*)sXn + swz(srow, sseg * 32 + 16)) = p1;
            *(short8*)((char*)sAgg + swz(srow, sseg * 32)) = ra0;
            *(short8*)((char*)sAgg + swz(srow, sseg * 32 + 16)) = ra1;
        }

        // ---- C: R/Z (K=256), N (K=128, A=mi), H (K=128, A=sXc) ----
        f32x4 aR[4] = {}, aZ[4] = {}, aN4[4] = {}, aH4[4] = {};
        #pragma unroll
        for (int ks = 0; ks < 8; ++ks) {
            short8 af[4];
            #pragma unroll
            for (int s4 = 0; s4 < 4; ++s4)
                af[s4] = (ks < 4)
                    ? *(const short8*)((const char*)sMi + swz(s4 * 16 + lo, ks * 64 + hi * 16))
                    : *(const short8*)((const char*)sXc + swz(s4 * 16 + lo, (ks - 4) * 64 + hi * 16));
            #pragma unroll
            for (int s4 = 0; s4 < 4; ++s4)
                aR[s4] = __builtin_amdgcn_mfma_f32_16x16x32_bf16(af[s4], wR[ks], aR[s4], 0, 0, 0);
            #pragma unroll
            for (int s4 = 0; s4 < 4; ++s4)
                aZ[s4] = __builtin_amdgcn_mfma_f32_16x16x32_bf16(af[s4], wZ[ks], aZ[s4], 0, 0, 0);
            if (ks < 4) {
                #pragma unroll
                for (int s4 = 0; s4 < 4; ++s4)
                    aN4[s4] = __builtin_amdgcn_mfma_f32_16x16x32_bf16(af[s4], wN[ks], aN4[s4], 0, 0, 0);
            } else {
                #pragma unroll
                for (int s4 = 0; s4 < 4; ++s4)
                    aH4[s4] = __builtin_amdgcn_mfma_f32_16x16x32_bf16(af[s4], wH[ks - 4], aH4[s4], 0, 0, 0);
            }
        }

        // ---- D: gates, state write, W_ro partial dot ----
        float pacc[4][4];
        #pragma unroll
        for (int s4 = 0; s4 < 4; ++s4)
            #pragma unroll
            for (int q = 0; q < 4; ++q) {
                int row = s4 * 16 + hi * 4 + q;
                float rg = sigm(aR[s4][q] + br);
                float zg = sigm(aZ[s4][q] + bz);
                float ng = tanhfast(aN4[s4][q] + bi + rg * (aH4[s4][q] + bh));
                float xv = bf2f(*(const unsigned short*)((const char*)sXc + swz(row, jcol * 2)));
                float ns = (1.f - zg) * ng + zg * xv;
                unsigned bits = bf16r(ns);
                unsigned other = (unsigned)__shfl_xor((int)bits, 1);
                if (!(lo & 1))
                    *(unsigned*)((char*)sSt + swz(row, jcol * 2)) = bits | (other << 16);
                pacc[s4][q] = ns * wro;
            }
        #pragma unroll
        for (int o = 1; o < 16; o <<= 1)
            #pragma unroll
            for (int s4 = 0; s4 < 4; ++s4)
                #pragma unroll
                for (int q = 0; q < 4; ++q)
                    pacc[s4][q] += __shfl_xor(pacc[s4][q], o);
        if (lo == 0) {
            #pragma unroll
            for (int s4 = 0; s4 < 4; ++s4)
                #pragma unroll
                for (int q = 0; q < 4; ++q)
                    pP[w][s4 * 16 + hi * 4 + q] = pacc[s4][q];
        }
        __syncthreads();   // bar1: sSt/pP/staged t+1 ready

        unsigned short* tmp = sXc; sXc = sXn; sXn = tmp;
    }

    // final loss consume (t=63) + block reduce
    if (tid < 64) {
        float out = bro;
        #pragma unroll
        for (int ww = 0; ww < 8; ++ww) out += pP[ww][tid];
        float d = out - tgtReg;
        lossAcc += 0.5f * d * d * mvReg;
        float v = lossAcc;
        #pragma unroll
        for (int o = 1; o < 64; o <<= 1) v += __shfl_xor(v, o);
        if (tid == 0) lossBlock[phys] = v;
    }
}

// ================= CSR build =================
__global__ void count_kernel(const int* __restrict__ dst, int* __restrict__ counts)
{
    int e = blockIdx.x * 256 + threadIdx.x;
    if (e < EE) atomicAdd(&counts[dst[e]], 1);
}

__global__ __launch_bounds__(1024)
void scan_kernel(const int* __restrict__ counts, int* __restrict__ off, int* __restrict__ cursor,
                 float* __restrict__ degf)
{
    __shared__ int s[1024];
    int tid = threadIdx.x;
    int base = tid * 4;
    int c[4]; int sum = 0;
    #pragma unroll
    for (int i = 0; i < 4; ++i) { c[i] = counts[base + i]; sum += c[i]; }
    s[tid] = sum; __syncthreads();
    for (int o = 1; o < 1024; o <<= 1) {
        int v = (tid >= o) ? s[tid - o] : 0;
        __syncthreads();
        s[tid] += v;
        __syncthreads();
    }
    int incl = s[tid];
    int run = incl - sum;
    #pragma unroll
    for (int i = 0; i < 4; ++i) {
        off[base + i] = run; cursor[base + i] = run;
        degf[base + i] = (float)c[i];
        run += c[i];
    }
    if (tid == 1023) off[4096] = incl;
}

__global__ void fill_kernel(const int* __restrict__ src, const int* __restrict__ dst,
                            int* __restrict__ cursor, int* __restrict__ csr_src)
{
    int e = blockIdx.x * 256 + threadIdx.x;
    if (e < EE) {
        int d = dst[e];
        int pos = atomicAdd(&cursor[d], 1);
        csr_src[pos] = src[e];
    }
}

// ================= mask detect / masked count =================
__global__ void detect_kernel(const unsigned char* __restrict__ maskb, int* __restrict__ flag)
{
    int i = blockIdx.x * 256 + threadIdx.x;
    bool hit = (i < BB * TT * NN) && (i & 3) && maskb[i];
    if (__any(hit) && (threadIdx.x & 63) == 0) atomicOr(flag, 1);
}

__global__ void masksum_kernel(const void* __restrict__ maskp, const int* __restrict__ flag,
                               float* __restrict__ den)
{
    int i = blockIdx.x * 256 + threadIdx.x;
    float v = 0.f;
    if (i < BB * TT * NN) {
        if (*flag) v = ((const unsigned char*)maskp)[i] ? 1.f : 0.f;
        else       v = ((const int*)maskp)[i] ? 1.f : 0.f;
    }
    #pragma unroll
    for (int o = 32; o > 0; o >>= 1) v += __shfl_down(v, o);
    __shared__ float sm[4];
    if ((threadIdx.x & 63) == 0) sm[threadIdx.x >> 6] = v;
    __syncthreads();
    if (threadIdx.x == 0) atomicAdd(den, sm[0] + sm[1] + sm[2] + sm[3]);
}

// ================= final reduce + dual-dtype output =================
__global__ __launch_bounds__(256)
void final_kernel(const float* __restrict__ lossBlock, const float* __restrict__ den,
                  unsigned* __restrict__ out)
{
    __shared__ float s[256];
    s[threadIdx.x] = lossBlock[threadIdx.x];
    __syncthreads();
    for (int o = 128; o > 0; o >>= 1) {
        if (threadIdx.x < o) s[threadIdx.x] += s[threadIdx.x + o];
        __syncthreads();
    }
    if (threadIdx.x == 0) {
        float L = s[0] / den[0];
        unsigned u = __float_as_uint(L);
        u += 0x7fffu + ((u >> 16) & 1u);
        unsigned hi = u >> 16;
        out[0] = hi * 0x10001u;   // bf16-exact low half; ~bf16 value as f32
    }
}

extern "C" void kernel_launch(void* const* d_in, const int* in_sizes, int n_in,
                              void* d_out, int out_size, void* d_ws, size_t ws_size,
                              hipStream_t stream)
{
    const float* x       = (const float*)d_in[0];
    const float* targets = (const float*)d_in[1];
    const float* W_msg   = (const float*)d_in[2];
    const float* b_msg   = (const float*)d_in[3];
    const float* W_mix   = (const float*)d_in[4];
    const float* b_mix   = (const float*)d_in[5];
    const float* W_ih    = (const float*)d_in[6];
    const float* b_ih    = (const float*)d_in[7];
    const float* W_hh    = (const float*)d_in[8];
    const float* b_hh    = (const float*)d_in[9];
    const float* W_ro    = (const float*)d_in[10];
    const float* b_ro    = (const float*)d_in[11];
    const void*  maskp   = d_in[12];
    const int*   esrc    = (const int*)d_in[13];
    const int*   edst    = (const int*)d_in[14];

    char* ws = (char*)d_ws;
    unsigned short* agg = (unsigned short*)ws; ws += (size_t)BB * TT * NN * HH * 2;  // 268 MB
    short* WcbP        = (short*)ws; ws += (size_t)4096 * 8 * 2;
    short* Wp4         = (short*)ws; ws += (size_t)32 * 8 * 64 * 8 * 2;
    float* biasRZ      = (float*)ws; ws += 256 * 4;
    float* bvec        = (float*)ws; ws += 128 * 4;
    float* degf        = (float*)ws; ws += 4096 * 4;
    float* lossBlock   = (float*)ws; ws += 256 * 4;
    int*   csr_off     = (int*)ws;   ws += 4104 * 4;
    int*   cursor      = (int*)ws;   ws += 4096 * 4;
    int*   counts      = (int*)ws;   ws += 4096 * 4;
    int*   csr_src     = (int*)ws;   ws += (size_t)EE * 4;
    int*   flag        = (int*)ws;   ws += 64;
    float* den         = (float*)ws; ws += 64;

    hipMemsetAsync(counts, 0, 4096 * 4, stream);
    hipMemsetAsync(flag, 0, 64, stream);
    hipMemsetAsync(den, 0, 4, stream);

    detect_kernel   <<<4096, 256, 0, stream>>>((const unsigned char*)maskp, flag);
    masksum_kernel  <<<4096, 256, 0, stream>>>(maskp, flag, den);
    count_kernel    <<<EE / 256, 256, 0, stream>>>(edst, counts);
    scan_kernel     <<<1, 1024, 0, stream>>>(counts, csr_off, cursor, degf);
    fill_kernel     <<<EE / 256, 256, 0, stream>>>(esrc, edst, cursor, csr_src);
    pack_wcb_kernel <<<16, 256, 0, stream>>>(W_msg, W_mix, WcbP);
    pack_ihh_kernel <<<64, 256, 0, stream>>>(W_ih, W_hh, Wp4);
    pack_bias_kernel<<<1, 128, 0, stream>>>(b_ih, b_hh, b_msg, W_mix, biasRZ, bvec);

    gather_all_kernel<<<(BB * TT * NN) / 4, 256, 0, stream>>>(x, csr_off, csr_src, agg);

    mega4_kernel<<<256, 512, 0, stream>>>(x, agg, WcbP, Wp4, degf, bvec, b_mix, biasRZ,
                                          b_ih, b_hh, W_ro, b_ro, targets, maskp, flag,
                                          lossBlock);
    final_kernel<<<1, 256, 0, stream>>>(lossBlock, den, (unsigned*)d_out);
}

// Round 9
// 2139.082 us; speedup vs baseline: 1.1141x; 1.1141x over previous
//
#include <hip/hip_runtime.h>
#include <hip/hip_bf16.h>
#include <stdint.h>

#define BB 4
#define TT 64
#define NN 4096
#define HH 128
#define EE 65536
#define BN (BB*NN)   // 16384

typedef __attribute__((ext_vector_type(8))) short short8;
typedef __attribute__((ext_vector_type(4))) float f32x4;

__device__ __forceinline__ unsigned short bf16r(float f) {
    unsigned u = __float_as_uint(f);
    u += 0x7fffu + ((u >> 16) & 1u);
    return (unsigned short)(u >> 16);
}
__device__ __forceinline__ float bf2f(unsigned bits16) {
    return __uint_as_float(bits16 << 16);
}
__device__ __forceinline__ float sigm(float x) { return 1.f / (1.f + __expf(-x)); }
__device__ __forceinline__ float tanhfast(float x) {
    return 1.f - 2.f / (__expf(2.f * x) + 1.f);
}
// byte address within a [64][128]-bf16 tile image, XOR-swizzled
__device__ __forceinline__ unsigned swz(int row, int colbyte) {
    return (unsigned)(row * 256 + (colbyte ^ ((row & 7) << 4)));
}

#define GLD_LDS16(g, s) __builtin_amdgcn_global_load_lds( \
    (const __attribute__((address_space(1))) void*)(g), \
    (__attribute__((address_space(3))) void*)(s), 16, 0, 0)

// ================= packs =================
__global__ void pack_wcb_kernel(const float* __restrict__ W_msg, const float* __restrict__ W_mix,
                                short* __restrict__ out)
{
    int idx = blockIdx.x * 256 + threadIdx.x;   // 4096
    if (idx >= 4096) return;
    int l = idx & 63, ks = (idx >> 6) & 3, nt = (idx >> 8) & 7, half = idx >> 11;
    int lo = l & 15, hi = l >> 4;
    int col = nt * 16 + lo;
    short8 v;
    #pragma unroll
    for (int i = 0; i < 8; ++i) {
        int k = ks * 32 + hi * 8 + i;
        float s;
        if (half == 0) {
            s = 0.f;
            for (int j = 0; j < 128; ++j) s += W_msg[k * 128 + j] * W_mix[j * 128 + col];
        } else {
            s = W_mix[(128 + k) * 128 + col];
        }
        v[i] = (short)bf16r(s);
    }
    *(short8*)(out + (size_t)idx * 8) = v;
}

__global__ void pack_ihh_kernel(const float* __restrict__ Wih, const float* __restrict__ Whh,
                                short* __restrict__ out)
{
    int idx = blockIdx.x * 256 + threadIdx.x;   // 16384
    if (idx >= 32 * 8 * 64) return;
    int l = idx & 63, ks = (idx >> 6) & 7, nt = idx >> 9;
    int lo = l & 15, hi = l >> 4;
    short8 v;
    #pragma unroll
    for (int i = 0; i < 8; ++i) {
        int k = ks * 32 + hi * 8 + i;
        float s = 0.f;
        if (nt < 16) {
            int col = nt * 16 + lo;
            s = (ks < 4) ? Wih[k * 384 + col] : Whh[(k - 128) * 384 + col];
        } else if (nt < 24) {
            int col = 256 + (nt - 16) * 16 + lo;
            s = (ks < 4) ? Wih[k * 384 + col] : 0.f;
        } else {
            int col = 256 + (nt - 24) * 16 + lo;
            s = (ks >= 4) ? Whh[(k - 128) * 384 + col] : 0.f;
        }
        v[i] = (short)bf16r(s);
    }
    *(short8*)(out + (size_t)idx * 8) = v;
}

__global__ void pack_bias_kernel(const float* __restrict__ b_ih, const float* __restrict__ b_hh,
                                 const float* __restrict__ b_msg, const float* __restrict__ W_mix,
                                 float* __restrict__ biasRZ, float* __restrict__ bvec)
{
    int j = threadIdx.x;
    biasRZ[j]       = b_ih[j]       + b_hh[j];
    biasRZ[128 + j] = b_ih[128 + j] + b_hh[128 + j];
    float s = 0.f;
    for (int jj = 0; jj < 128; ++jj) s += b_msg[jj] * W_mix[jj * 128 + j];
    bvec[j] = s;
}

// ================= x -> pre-swizzled bf16 tile image: ximg[phys*64+t][16KB] =================
__global__ __launch_bounds__(256)
void cvt_img_kernel(const float* __restrict__ x, char* __restrict__ ximg)
{
    int tileid = blockIdx.x;              // phys*64 + t
    int phys = tileid >> 6, t = tileid & 63;
    int b = phys >> 6, n0 = (phys & 63) * 64;
    const float* __restrict__ src = x + ((size_t)(b * TT + t) * NN + n0) * HH;
    char* __restrict__ dst = ximg + (size_t)tileid * 16384;
    int tid = threadIdx.x;
    #pragma unroll
    for (int u = 0; u < 4; ++u) {
        int unit = tid + u * 256;          // 1024 units of 16B
        int row = unit >> 4, g = unit & 15;
        const float* sp = src + row * HH + g * 8;
        float4 v0 = *(const float4*)sp;
        float4 v1 = *(const float4*)(sp + 4);
        short8 p;
        p[0] = (short)bf16r(v0.x); p[1] = (short)bf16r(v0.y);
        p[2] = (short)bf16r(v0.z); p[3] = (short)bf16r(v0.w);
        p[4] = (short)bf16r(v1.x); p[5] = (short)bf16r(v1.y);
        p[6] = (short)bf16r(v1.z); p[7] = (short)bf16r(v1.w);
        *(short8*)(dst + swz(row, g * 16)) = p;
    }
}

// ================= gather -> pre-swizzled agg image (8-deep unroll) =================
__global__ __launch_bounds__(256)
void gather_img_kernel(const float* __restrict__ x,
                       const int* __restrict__ off, const int* __restrict__ srcs,
                       char* __restrict__ aimg)
{
    int rb = blockIdx.x * 4 + (threadIdx.x >> 6);   // bt*4096 + dst
    int l = threadIdx.x & 63;
    int dst = rb & 4095;
    int bt  = rb >> 12;                              // b*64 + t
    const float* __restrict__ xr = x + (size_t)bt * NN * HH;
    int s = off[dst], e = off[dst + 1];
    float a0 = 0.f, a1 = 0.f;
    int i = s;
    for (; i + 7 < e; i += 8) {
        float2 v0 = *(const float2*)(xr + (size_t)srcs[i + 0] * HH + l * 2);
        float2 v1 = *(const float2*)(xr + (size_t)srcs[i + 1] * HH + l * 2);
        float2 v2 = *(const float2*)(xr + (size_t)srcs[i + 2] * HH + l * 2);
        float2 v3 = *(const float2*)(xr + (size_t)srcs[i + 3] * HH + l * 2);
        float2 v4 = *(const float2*)(xr + (size_t)srcs[i + 4] * HH + l * 2);
        float2 v5 = *(const float2*)(xr + (size_t)srcs[i + 5] * HH + l * 2);
        float2 v6 = *(const float2*)(xr + (size_t)srcs[i + 6] * HH + l * 2);
        float2 v7 = *(const float2*)(xr + (size_t)srcs[i + 7] * HH + l * 2);
        a0 += ((v0.x + v1.x) + (v2.x + v3.x)) + ((v4.x + v5.x) + (v6.x + v7.x));
        a1 += ((v0.y + v1.y) + (v2.y + v3.y)) + ((v4.y + v5.y) + (v6.y + v7.y));
    }
    for (; i + 1 < e; i += 2) {
        float2 v0 = *(const float2*)(xr + (size_t)srcs[i] * HH + l * 2);
        float2 v1 = *(const float2*)(xr + (size_t)srcs[i + 1] * HH + l * 2);
        a0 += v0.x + v1.x; a1 += v0.y + v1.y;
    }
    if (i < e) {
        float2 v0 = *(const float2*)(xr + (size_t)srcs[i] * HH + l * 2);
        a0 += v0.x; a1 += v0.y;
    }
    int b = bt >> 6, t = bt & 63;
    int phys = (b << 6) | (dst >> 6);
    int row = dst & 63;
    size_t tile = ((size_t)phys * TT + t) * 16384;
    *(unsigned*)(aimg + tile + swz(row, l * 4)) =
        (unsigned)bf16r(a0) | ((unsigned)bf16r(a1) << 16);
}

// ================= persistent T-loop: global_load_lds double-buffered staging =================
__global__ __launch_bounds__(512, 2)
void mega5_kernel(const char* __restrict__ ximg, const char* __restrict__ aimg,
                  const short* __restrict__ WcbP, const short* __restrict__ Wp4,
                  const float* __restrict__ degf,
                  const float* __restrict__ bvec, const float* __restrict__ b_mix,
                  const float* __restrict__ biasRZ,
                  const float* __restrict__ b_ih, const float* __restrict__ b_hh,
                  const float* __restrict__ W_ro, const float* __restrict__ b_ro,
                  const float* __restrict__ targets, const void* __restrict__ maskp,
                  const int* __restrict__ flag,
                  float* __restrict__ lossBlock)
{
    __shared__ char sX[2][16384];
    __shared__ char sA[2][16384];
    __shared__ char sMi[16384];
    __shared__ char sSt[16384];
    __shared__ float pP[8][64];
    __shared__ float sdeg[64];

    const int tid = threadIdx.x;
    const int w = tid >> 6, l = tid & 63, lo = l & 15, hi = l >> 4;
    const int nt = w;
    const int phys = blockIdx.x;
    const int b = phys >> 6;
    const int n0 = (phys & 63) * 64;
    const size_t tbase = (size_t)phys * TT * 16384;

    // ---- all B-fragments in registers, loaded once ----
    short8 wB[8], wR[8], wZ[8], wN[4], wH[4];
    #pragma unroll
    for (int ks = 0; ks < 8; ++ks) {
        wB[ks] = *(const short8*)(WcbP + (size_t)((((ks >> 2) * 8 + nt) * 4 + (ks & 3)) * 64 + l) * 8);
        wR[ks] = *(const short8*)(Wp4 + (size_t)((nt * 8 + ks) * 64 + l) * 8);
        wZ[ks] = *(const short8*)(Wp4 + (size_t)(((8 + nt) * 8 + ks) * 64 + l) * 8);
    }
    #pragma unroll
    for (int ks = 0; ks < 4; ++ks) {
        wN[ks] = *(const short8*)(Wp4 + (size_t)(((16 + nt) * 8 + ks) * 64 + l) * 8);
        wH[ks] = *(const short8*)(Wp4 + (size_t)(((24 + nt) * 8 + (ks + 4)) * 64 + l) * 8);
    }

    const int jcol = nt * 16 + lo;
    const float br = biasRZ[jcol], bz = biasRZ[128 + jcol];
    const float bi = b_ih[256 + jcol], bh = b_hh[256 + jcol];
    const float wro = W_ro[jcol];
    const float bv = bvec[jcol], bm = b_mix[jcol];
    const float bro = b_ro[0];
    const int fl = *flag;

    // ---- prologue: async-stage t=0, zero state, first targets prefetch ----
    {
        const char* gx = ximg + tbase + (w * 2) * 1024 + l * 16;
        const char* ga = aimg + tbase + (w * 2) * 1024 + l * 16;
        GLD_LDS16(gx,        sX[0] + (w * 2) * 1024);
        GLD_LDS16(gx + 1024, sX[0] + (w * 2 + 1) * 1024);
        GLD_LDS16(ga,        sA[0] + (w * 2) * 1024);
        GLD_LDS16(ga + 1024, sA[0] + (w * 2 + 1) * 1024);
    }
    #pragma unroll
    for (int it = 0; it < 8; ++it) ((unsigned*)sSt)[tid + it * 512] = 0u;
    if (tid < 64) sdeg[tid] = degf[n0 + tid];

    float tgtReg = 0.f, mvReg = 0.f, lossAcc = 0.f;
    if (tid < 64) {
        size_t ti = (size_t)(b * TT) * NN + n0 + tid;
        tgtReg = targets[ti];
        mvReg = fl ? (((const unsigned char*)maskp)[ti] ? 1.f : 0.f)
                   : (((const int*)maskp)[ti] ? 1.f : 0.f);
    }
    __syncthreads();   // drains prologue staging

    char* sXc = sX[0]; char* sXn = sX[1];
    char* sAc = sA[0]; char* sAn = sA[1];

    for (int t = 0; t < TT; ++t) {
        // ---- loss consume for t-1 + targets prefetch for t ----
        float tgtNew = tgtReg, mvNew = mvReg;
        if (tid < 64) {
            if (t > 0) {
                float out = bro;
                #pragma unroll
                for (int ww = 0; ww < 8; ++ww) out += pP[ww][tid];
                float d = out - tgtReg;
                lossAcc += 0.5f * d * d * mvReg;
            }
            size_t ti = (size_t)(b * TT + t) * NN + n0 + tid;
            tgtNew = targets[ti];
            mvNew = fl ? (((const unsigned char*)maskp)[ti] ? 1.f : 0.f)
                       : (((const int*)maskp)[ti] ? 1.f : 0.f);
        }
        tgtReg = tgtNew; mvReg = mvNew;

        // ---- issue async staging for t+1 (drained at end-of-step __syncthreads) ----
        if (t + 1 < TT) {
            const size_t toff = tbase + (size_t)(t + 1) * 16384;
            const char* gx = ximg + toff + (w * 2) * 1024 + l * 16;
            const char* ga = aimg + toff + (w * 2) * 1024 + l * 16;
            GLD_LDS16(gx,        sXn + (w * 2) * 1024);
            GLD_LDS16(gx + 1024, sXn + (w * 2 + 1) * 1024);
            GLD_LDS16(ga,        sAn + (w * 2) * 1024);
            GLD_LDS16(ga + 1024, sAn + (w * 2 + 1) * 1024);
        }

        // ---- B: mi = agg@Wc + state@Wb + deg*bvec + b_mix ----
        f32x4 mAcc[4] = {};
        #pragma unroll
        for (int ks = 0; ks < 8; ++ks) {
            #pragma unroll
            for (int s4 = 0; s4 < 4; ++s4) {
                short8 af = (ks < 4)
                    ? *(const short8*)(sAc + swz(s4 * 16 + lo, ks * 64 + hi * 16))
                    : *(const short8*)(sSt + swz(s4 * 16 + lo, (ks - 4) * 64 + hi * 16));
                mAcc[s4] = __builtin_amdgcn_mfma_f32_16x16x32_bf16(af, wB[ks], mAcc[s4], 0, 0, 0);
            }
        }
        #pragma unroll
        for (int s4 = 0; s4 < 4; ++s4)
            #pragma unroll
            for (int q = 0; q < 4; ++q) {
                int row = s4 * 16 + hi * 4 + q;
                float v = mAcc[s4][q] + sdeg[row] * bv + bm;
                unsigned bits = bf16r(v);
                unsigned other = (unsigned)__shfl_xor((int)bits, 1);
                if (!(lo & 1))
                    *(unsigned*)(sMi + swz(row, jcol * 2)) = bits | (other << 16);
            }

        // ---- mid-step barrier: LDS-only wait (keep staging loads in flight!) ----
        asm volatile("s_waitcnt lgkmcnt(0)" ::: "memory");
        __builtin_amdgcn_sched_barrier(0);
        __builtin_amdgcn_s_barrier();
        __builtin_amdgcn_sched_barrier(0);

        // ---- C: R/Z (K=256), N (K=128, A=mi), H (K=128, A=sXc) ----
        f32x4 aR[4] = {}, aZ[4] = {}, aN4[4] = {}, aH4[4] = {};
        #pragma unroll
        for (int ks = 0; ks < 8; ++ks) {
            short8 af[4];
            #pragma unroll
            for (int s4 = 0; s4 < 4; ++s4)
                af[s4] = (ks < 4)
                    ? *(const short8*)(sMi + swz(s4 * 16 + lo, ks * 64 + hi * 16))
                    : *(const short8*)(sXc + swz(s4 * 16 + lo, (ks - 4) * 64 + hi * 16));
            #pragma unroll
            for (int s4 = 0; s4 < 4; ++s4)
                aR[s4] = __builtin_amdgcn_mfma_f32_16x16x32_bf16(af[s4], wR[ks], aR[s4], 0, 0, 0);
            #pragma unroll
            for (int s4 = 0; s4 < 4; ++s4)
                aZ[s4] = __builtin_amdgcn_mfma_f32_16x16x32_bf16(af[s4], wZ[ks], aZ[s4], 0, 0, 0);
            if (ks < 4) {
                #pragma unroll
                for (int s4 = 0; s4 < 4; ++s4)
                    aN4[s4] = __builtin_amdgcn_mfma_f32_16x16x32_bf16(af[s4], wN[ks], aN4[s4], 0, 0, 0);
            } else {
                #pragma unroll
                for (int s4 = 0; s4 < 4; ++s4)
                    aH4[s4] = __builtin_amdgcn_mfma_f32_16x16x32_bf16(af[s4], wH[ks - 4], aH4[s4], 0, 0, 0);
            }
        }

        // ---- D: gates, state write, W_ro partial dot ----
        float pacc[4][4];
        #pragma unroll
        for (int s4 = 0; s4 < 4; ++s4)
            #pragma unroll
            for (int q = 0; q < 4; ++q) {
                int row = s4 * 16 + hi * 4 + q;
                float rg = sigm(aR[s4][q] + br);
                float zg = sigm(aZ[s4][q] + bz);
                float ng = tanhfast(aN4[s4][q] + bi + rg * (aH4[s4][q] + bh));
                float xv = bf2f(*(const unsigned short*)(sXc + swz(row, jcol * 2)));
                float ns = (1.f - zg) * ng + zg * xv;
                unsigned bits = bf16r(ns);
                unsigned other = (unsigned)__shfl_xor((int)bits, 1);
                if (!(lo & 1))
                    *(unsigned*)(sSt + swz(row, jcol * 2)) = bits | (other << 16);
                pacc[s4][q] = ns * wro;
            }
        #pragma unroll
        for (int o = 1; o < 16; o <<= 1)
            #pragma unroll
            for (int s4 = 0; s4 < 4; ++s4)
                #pragma unroll
                for (int q = 0; q < 4; ++q)
                    pacc[s4][q] += __shfl_xor(pacc[s4][q], o);
        if (lo == 0) {
            #pragma unroll
            for (int s4 = 0; s4 < 4; ++s4)
                #pragma unroll
                for (int q = 0; q < 4; ++q)
                    pP[w][s4 * 16 + hi * 4 + q] = pacc[s4][q];
        }
        __syncthreads();   // full drain: staged t+1 landed; sSt/pP published

        char* tp = sXc; sXc = sXn; sXn = tp;
        tp = sAc; sAc = sAn; sAn = tp;
    }

    // final loss consume (t=63) + block reduce
    if (tid < 64) {
        float out = bro;
        #pragma unroll
        for (int ww = 0; ww < 8; ++ww) out += pP[ww][tid];
        float d = out - tgtReg;
        lossAcc += 0.5f * d * d * mvReg;
        float v = lossAcc;
        #pragma unroll
        for (int o = 1; o < 64; o <<= 1) v += __shfl_xor(v, o);
        if (tid == 0) lossBlock[phys] = v;
    }
}

// ================= CSR build =================
__global__ void count_kernel(const int* __restrict__ dst, int* __restrict__ counts)
{
    int e = blockIdx.x * 256 + threadIdx.x;
    if (e < EE) atomicAdd(&counts[dst[e]], 1);
}

__global__ __launch_bounds__(1024)
void scan_kernel(const int* __restrict__ counts, int* __restrict__ off, int* __restrict__ cursor,
                 float* __restrict__ degf)
{
    __shared__ int s[1024];
    int tid = threadIdx.x;
    int base = tid * 4;
    int c[4]; int sum = 0;
    #pragma unroll
    for (int i = 0; i < 4; ++i) { c[i] = counts[base + i]; sum += c[i]; }
    s[tid] = sum; __syncthreads();
    for (int o = 1; o < 1024; o <<= 1) {
        int v = (tid >= o) ? s[tid - o] : 0;
        __syncthreads();
        s[tid] += v;
        __syncthreads();
    }
    int incl = s[tid];
    int run = incl - sum;
    #pragma unroll
    for (int i = 0; i < 4; ++i) {
        off[base + i] = run; cursor[base + i] = run;
        degf[base + i] = (float)c[i];
        run += c[i];
    }
    if (tid == 1023) off[4096] = incl;
}

__global__ void fill_kernel(const int* __restrict__ src, const int* __restrict__ dst,
                            int* __restrict__ cursor, int* __restrict__ csr_src)
{
    int e = blockIdx.x * 256 + threadIdx.x;
    if (e < EE) {
        int d = dst[e];
        int pos = atomicAdd(&cursor[d], 1);
        csr_src[pos] = src[e];
    }
}

// ================= mask detect / masked count =================
__global__ void detect_kernel(const unsigned char* __restrict__ maskb, int* __restrict__ flag)
{
    int i = blockIdx.x * 256 + threadIdx.x;
    bool hit = (i < BB * TT * NN) && (i & 3) && maskb[i];
    if (__any(hit) && (threadIdx.x & 63) == 0) atomicOr(flag, 1);
}

__global__ void masksum_kernel(const void* __restrict__ maskp, const int* __restrict__ flag,
                               float* __restrict__ den)
{
    int i = blockIdx.x * 256 + threadIdx.x;
    float v = 0.f;
    if (i < BB * TT * NN) {
        if (*flag) v = ((const unsigned char*)maskp)[i] ? 1.f : 0.f;
        else       v = ((const int*)maskp)[i] ? 1.f : 0.f;
    }
    #pragma unroll
    for (int o = 32; o > 0; o >>= 1) v += __shfl_down(v, o);
    __shared__ float sm[4];
    if ((threadIdx.x & 63) == 0) sm[threadIdx.x >> 6] = v;
    __syncthreads();
    if (threadIdx.x == 0) atomicAdd(den, sm[0] + sm[1] + sm[2] + sm[3]);
}

// ================= final reduce + dual-dtype output =================
__global__ __launch_bounds__(256)
void final_kernel(const float* __restrict__ lossBlock, const float* __restrict__ den,
                  unsigned* __restrict__ out)
{
    __shared__ float s[256];
    s[threadIdx.x] = lossBlock[threadIdx.x];
    __syncthreads();
    for (int o = 128; o > 0; o >>= 1) {
        if (threadIdx.x < o) s[threadIdx.x] += s[threadIdx.x + o];
        __syncthreads();
    }
    if (threadIdx.x == 0) {
        float L = s[0] / den[0];
        unsigned u = __float_as_uint(L);
        u += 0x7fffu + ((u >> 16) & 1u);
        unsigned hi = u >> 16;
        out[0] = hi * 0x10001u;   // bf16-exact low half; ~bf16 value as f32
    }
}

extern "C" void kernel_launch(void* const* d_in, const int* in_sizes, int n_in,
                              void* d_out, int out_size, void* d_ws, size_t ws_size,
                              hipStream_t stream)
{
    const float* x       = (const float*)d_in[0];
    const float* targets = (const float*)d_in[1];
    const float* W_msg   = (const float*)d_in[2];
    const float* b_msg   = (const float*)d_in[3];
    const float* W_mix   = (const float*)d_in[4];
    const float* b_mix   = (const float*)d_in[5];
    const float* W_ih    = (const float*)d_in[6];
    const float* b_ih    = (const float*)d_in[7];
    const float* W_hh    = (const float*)d_in[8];
    const float* b_hh    = (const float*)d_in[9];
    const float* W_ro    = (const float*)d_in[10];
    const float* b_ro    = (const float*)d_in[11];
    const void*  maskp   = d_in[12];
    const int*   esrc    = (const int*)d_in[13];
    const int*   edst    = (const int*)d_in[14];

    char* ws = (char*)d_ws;
    char* ximg = ws; ws += (size_t)16384 * 16384;   // 268 MB pre-swizzled x tiles
    char* aimg = ws; ws += (size_t)16384 * 16384;   // 268 MB pre-swizzled agg tiles
    short* WcbP        = (short*)ws; ws += (size_t)4096 * 8 * 2;
    short* Wp4         = (short*)ws; ws += (size_t)32 * 8 * 64 * 8 * 2;
    float* biasRZ      = (float*)ws; ws += 256 * 4;
    float* bvec        = (float*)ws; ws += 128 * 4;
    float* degf        = (float*)ws; ws += 4096 * 4;
    float* lossBlock   = (float*)ws; ws += 256 * 4;
    int*   csr_off     = (int*)ws;   ws += 4104 * 4;
    int*   cursor      = (int*)ws;   ws += 4096 * 4;
    int*   counts      = (int*)ws;   ws += 4096 * 4;
    int*   csr_src     = (int*)ws;   ws += (size_t)EE * 4;
    int*   flag        = (int*)ws;   ws += 64;
    float* den         = (float*)ws; ws += 64;

    hipMemsetAsync(counts, 0, 4096 * 4, stream);
    hipMemsetAsync(flag, 0, 64, stream);
    hipMemsetAsync(den, 0, 4, stream);

    detect_kernel   <<<4096, 256, 0, stream>>>((const unsigned char*)maskp, flag);
    masksum_kernel  <<<4096, 256, 0, stream>>>(maskp, flag, den);
    count_kernel    <<<EE / 256, 256, 0, stream>>>(edst, counts);
    scan_kernel     <<<1, 1024, 0, stream>>>(counts, csr_off, cursor, degf);
    fill_kernel     <<<EE / 256, 256, 0, stream>>>(esrc, edst, cursor, csr_src);
    pack_wcb_kernel <<<16, 256, 0, stream>>>(W_msg, W_mix, WcbP);
    pack_ihh_kernel <<<64, 256, 0, stream>>>(W_ih, W_hh, Wp4);
    pack_bias_kernel<<<1, 128, 0, stream>>>(b_ih, b_hh, b_msg, W_mix, biasRZ, bvec);

    cvt_img_kernel   <<<16384, 256, 0, stream>>>(x, ximg);
    gather_img_kernel<<<(BB * TT * NN) / 4, 256, 0, stream>>>(x, csr_off, csr_src, aimg);

    mega5_kernel<<<256, 512, 0, stream>>>(ximg, aimg, WcbP, Wp4, degf, bvec, b_mix, biasRZ,
                                          b_ih, b_hh, W_ro, b_ro, targets, maskp, flag,
                                          lossBlock);
    final_kernel<<<1, 256, 0, stream>>>(lossBlock, den, (unsigned*)d_out);
}